// Round 5
// baseline (10256.654 us; speedup 1.0000x reference)
//
#include <hip/hip_runtime.h>
#include <hip/hip_bf16.h>
#include <stdint.h>

typedef unsigned short u16;

#define NB  32
#define NT  4096
#define NDZ 128
#define NG  384   // 3*DZ
#define NIN 192   // IN_DIM

// ---------- helpers ----------
__device__ __forceinline__ float fast_rcp(float x) { return __builtin_amdgcn_rcpf(x); }
__device__ __forceinline__ float sigmoid_f(float x) { return fast_rcp(1.f + __expf(-x)); }
__device__ __forceinline__ float tanh_f(float x) {
  return 1.f - 2.f * fast_rcp(1.f + __expf(2.f * x));
}
__device__ __forceinline__ u16 f2bf(float f) {
  unsigned u = __float_as_uint(f);
  return (u16)((u + 0x7fffu + ((u >> 16) & 1u)) >> 16);
}

// LDS-only barrier (ds ops drained via lgkmcnt; vmcnt stays in flight so the
// t+2 gi prefetch and traj stores cross barriers without draining).
__device__ __forceinline__ void bar_lds() {
  asm volatile("s_waitcnt lgkmcnt(0)\n\ts_barrier" ::: "memory");
}

// gi workspace: bf16 validated (absmax 3.9e-3 << 5.9e-2); f32 if ws allows
__device__ __forceinline__ void store8(float* p, const float* v) {
  float4 a = {v[0], v[1], v[2], v[3]}, b = {v[4], v[5], v[6], v[7]};
  *(float4*)p = a; *(float4*)(p + 4) = b;
}
__device__ __forceinline__ void store8(u16* p, const float* v) {
  uint4 o;
  o.x = (unsigned)f2bf(v[0]) | ((unsigned)f2bf(v[1]) << 16);
  o.y = (unsigned)f2bf(v[2]) | ((unsigned)f2bf(v[3]) << 16);
  o.z = (unsigned)f2bf(v[4]) | ((unsigned)f2bf(v[5]) << 16);
  o.w = (unsigned)f2bf(v[6]) | ((unsigned)f2bf(v[7]) << 16);
  *(uint4*)p = o;
}

// ---------- Phase 1: gi = x @ W_ih^T + b_ih (unchanged) ----------
#define GM 128
#define GN 128
#define LDSS 132

template <typename GT>
__global__ __launch_bounds__(256) void gemm_gi(
    const float* __restrict__ Y, const float* __restrict__ M,
    const float* __restrict__ H, const float* __restrict__ Wih,
    const float* __restrict__ bih, GT* __restrict__ gi)
{
  __shared__ float As[32 * LDSS];
  __shared__ float Bs[32 * LDSS];
  const int tid = threadIdx.x;
  const size_t m0 = (size_t)blockIdx.x * GM;
  const int n0 = blockIdx.y * GN;
  const int tm = tid & 15;
  const int tn = tid >> 4;

  float acc[8][8];
#pragma unroll
  for (int i = 0; i < 8; ++i)
#pragma unroll
    for (int j = 0; j < 8; ++j) acc[i][j] = 0.f;

#pragma unroll
  for (int kc = 0; kc < 6; ++kc) {
    const float* src; int stride; int off;
    if (kc == 0)      { src = Y; stride = 32;  off = 0; }
    else if (kc == 1) { src = M; stride = 32;  off = 0; }
    else              { src = H; stride = 128; off = (kc - 2) * 32; }
#pragma unroll
    for (int it = 0; it < 4; ++it) {
      int x = tid + it * 256;
      int row = x >> 3, q = x & 7;
      float4 v = *(const float4*)(src + (m0 + (size_t)row) * stride + off + q * 4);
      As[(q * 4 + 0) * LDSS + row] = v.x;
      As[(q * 4 + 1) * LDSS + row] = v.y;
      As[(q * 4 + 2) * LDSS + row] = v.z;
      As[(q * 4 + 3) * LDSS + row] = v.w;
    }
#pragma unroll
    for (int it = 0; it < 4; ++it) {
      int x = tid + it * 256;
      int g = x >> 3, q = x & 7;
      float4 v = *(const float4*)(Wih + (size_t)(n0 + g) * NIN + kc * 32 + q * 4);
      Bs[(q * 4 + 0) * LDSS + g] = v.x;
      Bs[(q * 4 + 1) * LDSS + g] = v.y;
      Bs[(q * 4 + 2) * LDSS + g] = v.z;
      Bs[(q * 4 + 3) * LDSS + g] = v.w;
    }
    __syncthreads();
#pragma unroll
    for (int kk = 0; kk < 32; ++kk) {
      float4 a0 = *(const float4*)&As[kk * LDSS + tm * 8];
      float4 a1 = *(const float4*)&As[kk * LDSS + tm * 8 + 4];
      float4 b0 = *(const float4*)&Bs[kk * LDSS + tn * 8];
      float4 b1 = *(const float4*)&Bs[kk * LDSS + tn * 8 + 4];
      float av[8] = {a0.x, a0.y, a0.z, a0.w, a1.x, a1.y, a1.z, a1.w};
      float bv[8] = {b0.x, b0.y, b0.z, b0.w, b1.x, b1.y, b1.z, b1.w};
#pragma unroll
      for (int i = 0; i < 8; ++i)
#pragma unroll
        for (int j = 0; j < 8; ++j)
          acc[i][j] = __builtin_fmaf(av[i], bv[j], acc[i][j]);
    }
    __syncthreads();
  }
  float bv[8];
#pragma unroll
  for (int j = 0; j < 8; ++j) bv[j] = bih[n0 + tn * 8 + j];
#pragma unroll
  for (int i = 0; i < 8; ++i) {
    size_t row = m0 + (size_t)(tm * 8 + i);
    GT* o = gi + row * NG + n0 + tn * 8;
    float v[8];
#pragma unroll
    for (int j = 0; j < 8; ++j) v[j] = acc[i][j] + bv[j];
    store8(o, v);
  }
}

// ---------- Phase 2: batched-MFMA scan ----------
// R1-R3 all pinned at ~1860 cyc/step: the per-step serial chain is
// irreducible at batch=1. Fix: amortize it over 16 batches/block.
// Per step: gh(384x16) = Whh(384x128) @ Z(128x16) via mfma_f32_16x16x32_bf16.
// 2 blocks x 16 batches, 8 waves; wave w owns row-tiles {w, w+8, w+16}
// (r/u/n rows for elems [16w,16w+16)) -> 12 MFMA/step/wave.
// D layout (m89-verified): col=lane&15=batch, row=4q+reg=elem. So
// r[j],u[j],n[j] land in the SAME lane, different accs -> gates lane-local.
// Only cross-wave data is Z: 1 ds_write_b64 + 4 ds_read_b128 per wave per
// step into double-buffered LDS (KPAD pad for bank balance) -> 1 barrier.
// A/B frags use identical (lane,slot)->k maps, so any HW k-permutation
// cancels in the reduction. Whh + z_d in bf16 (like validated bf16 gi).
#define BPB  16    // batches per block
#define KPAD 136   // Z row pitch in bf16 (pad 8 -> bank-balanced b128 reads)

typedef __attribute__((ext_vector_type(8))) __bf16 bfrag;
typedef __attribute__((ext_vector_type(4))) float ffrag;

template <typename GT> struct Raw;
template <> struct Raw<u16>   { using T = uint2;  };
template <> struct Raw<float> { using T = float4; };

__device__ __forceinline__ void unpk(const uint2& u, float* v) {
  v[0] = __uint_as_float(u.x << 16);
  v[1] = __uint_as_float(u.x & 0xffff0000u);
  v[2] = __uint_as_float(u.y << 16);
  v[3] = __uint_as_float(u.y & 0xffff0000u);
}
__device__ __forceinline__ void unpk(const float4& f, float* v) {
  v[0] = f.x; v[1] = f.y; v[2] = f.z; v[3] = f.w;
}

template <typename GT>
__global__ __launch_bounds__(512, 2) void scan_m(
    const float* __restrict__ zinit, const float* __restrict__ tdyn,
    const int* __restrict__ lens, const float* __restrict__ Whh,
    const float* __restrict__ bhh, const float* __restrict__ lgam,
    const GT* __restrict__ gi, float* __restrict__ out)
{
  const int tid  = threadIdx.x;    // 0..511
  const int lane = tid & 63;
  const int w    = tid >> 6;       // wave 0..7 -> elem tile [16w,16w+16)
  const int q    = lane >> 4;      // k-chunk / row-quad 0..3
  const int bl   = lane & 15;      // batch within block
  const int batch = blockIdx.x * BPB + bl;
  const int j0   = 16 * w + 4 * q; // first of 4 owned elems

  __shared__ __align__(16) u16 ZL0[BPB * KPAD];  // 4.25 KB each
  __shared__ __align__(16) u16 ZL1[BPB * KPAD];

  // ---- A fragments: Whh bf16. Tile g rows g*128+[16w,16w+16);
  //      A row = lane&15, k = 32kk + 8q + i ----
  union BU { bfrag v; u16 s[8]; };
  bfrag afr0[4], afr1[4], afr2[4];
#pragma unroll
  for (int g = 0; g < 3; ++g) {
    const float* wr = Whh + (size_t)(g * NDZ + 16 * w + bl) * NDZ;
#pragma unroll
    for (int kk = 0; kk < 4; ++kk) {
      float4 v0 = *(const float4*)(wr + 32 * kk + 8 * q);
      float4 v1 = *(const float4*)(wr + 32 * kk + 8 * q + 4);
      BU u;
      u.s[0] = f2bf(v0.x); u.s[1] = f2bf(v0.y); u.s[2] = f2bf(v0.z); u.s[3] = f2bf(v0.w);
      u.s[4] = f2bf(v1.x); u.s[5] = f2bf(v1.y); u.s[6] = f2bf(v1.z); u.s[7] = f2bf(v1.w);
      if (g == 0) afr0[kk] = u.v;
      else if (g == 1) afr1[kk] = u.v;
      else afr2[kk] = u.v;
    }
  }

  const int len = lens[batch];
  const float* tp = tdyn + (size_t)batch * NT;
  const GT* gl = gi + ((size_t)batch * NT) * NG + j0;   // lane's gi base
  float* traj = out + (size_t)NB * NDZ + (size_t)batch * NT * NDZ;

  // per-lane state: 4 elems (j0..j0+3) of its batch
  float zc[4], gam[4], bg0[4], bg1[4], bg2[4];
  {
    float4 z4 = *(const float4*)(zinit + batch * NDZ + j0);
    zc[0] = z4.x; zc[1] = z4.y; zc[2] = z4.z; zc[3] = z4.w;
    float4 l4 = *(const float4*)(lgam + j0);
    float lgv[4] = {l4.x, l4.y, l4.z, l4.w};
#pragma unroll
    for (int r = 0; r < 4; ++r)
      gam[r] = (lgv[r] > 15.f) ? lgv[r] : __logf(1.f + __expf(lgv[r]));
    float4 b0 = *(const float4*)(bhh + j0);
    float4 b1 = *(const float4*)(bhh + NDZ + j0);
    float4 b2 = *(const float4*)(bhh + 2 * NDZ + j0);
    bg0[0] = b0.x; bg0[1] = b0.y; bg0[2] = b0.z; bg0[3] = b0.w;
    bg1[0] = b1.x; bg1[1] = b1.y; bg1[2] = b1.z; bg1[3] = b1.w;
    bg2[0] = b2.x; bg2[1] = b2.y; bg2[2] = b2.z; bg2[3] = b2.w;
  }
  float t_prev = tp[0];

  using RT = typename Raw<GT>::T;
  // prefetch buffers (static names; 2-step lead)
  float ptkA = tp[0], ptkB = tp[1];
  RT prA0 = *(const RT*)(gl);
  RT prA1 = *(const RT*)(gl + NDZ);
  RT prA2 = *(const RT*)(gl + 2 * NDZ);
  RT prB0 = *(const RT*)(gl + NG);
  RT prB1 = *(const RT*)(gl + NG + NDZ);
  RT prB2 = *(const RT*)(gl + NG + 2 * NDZ);

  auto stepf = [&](u16* ZB, float& ptkX, RT& px0, RT& px1, RT& px2, int t) {
    // --- z_d for step t (inputs all prefetched / in-reg) ---
    const float tk = ptkX;
    const float dtv = fmaxf(tk - t_prev, 0.f);
    t_prev = tk;
    float zd[4];
#pragma unroll
    for (int r = 0; r < 4; ++r) zd[r] = zc[r] * __expf(-gam[r] * dtv);
    // publish Z[batch][j0..j0+3] as bf16 (one b64 write)
    unsigned p0 = (unsigned)f2bf(zd[0]) | ((unsigned)f2bf(zd[1]) << 16);
    unsigned p1 = (unsigned)f2bf(zd[2]) | ((unsigned)f2bf(zd[3]) << 16);
    *(uint2*)&ZB[bl * KPAD + j0] = uint2{p0, p1};
    bar_lds();  // ONLY barrier of the step (ZL double-buffered)

    // --- B frags (Z col = lane&15 = batch, k = 32kk+8q+i) + MFMA ---
    ffrag acc0 = {0.f, 0.f, 0.f, 0.f}, acc1 = acc0, acc2 = acc0;
#pragma unroll
    for (int kk = 0; kk < 4; ++kk) {
      bfrag bf = *(const bfrag*)&ZB[bl * KPAD + 32 * kk + 8 * q];
      acc0 = __builtin_amdgcn_mfma_f32_16x16x32_bf16(afr0[kk], bf, acc0, 0, 0, 0);
      acc1 = __builtin_amdgcn_mfma_f32_16x16x32_bf16(afr1[kk], bf, acc1, 0, 0, 0);
      acc2 = __builtin_amdgcn_mfma_f32_16x16x32_bf16(afr2[kk], bf, acc2, 0, 0, 0);
    }

    // --- gates: lane-local (D row 4q+r = elem j0+r, col = batch) ---
    float gr[4], gu[4], gn[4];
    unpk(px0, gr); unpk(px1, gu); unpk(px2, gn);
    const bool act = (t < len);   // per-batch mask
    float zo[4];
#pragma unroll
    for (int r = 0; r < 4; ++r) {
      const float rr = sigmoid_f(acc0[r] + bg0[r] + gr[r]);
      const float uu = sigmoid_f(acc1[r] + bg1[r] + gu[r]);
      const float nn = tanh_f(__builtin_fmaf(rr, acc2[r] + bg2[r], gn[r]));
      const float zn = (1.f - uu) * nn + uu * zd[r];
      zo[r] = act ? zn : zd[r];
      zc[r] = zo[r];
    }
    *(float4*)(traj + (size_t)t * NDZ + j0) = float4{zo[0], zo[1], zo[2], zo[3]};

    // --- prefetch t+2 (clamped; values past end unused) ---
    const int t2 = (t + 2 < NT) ? (t + 2) : (NT - 1);
    ptkX = tp[t2];
    const GT* g2 = gl + (size_t)t2 * NG;
    px0 = *(const RT*)(g2);
    px1 = *(const RT*)(g2 + NDZ);
    px2 = *(const RT*)(g2 + 2 * NDZ);
  };

  for (int t = 0; t < NT; t += 2) {
    stepf(ZL0, ptkA, prA0, prA1, prA2, t);
    stepf(ZL1, ptkB, prB0, prB1, prB2, t + 1);
  }
  *(float4*)(out + batch * NDZ + j0) = float4{zc[0], zc[1], zc[2], zc[3]};  // z_final
}

extern "C" void kernel_launch(void* const* d_in, const int* in_sizes, int n_in,
                              void* d_out, int out_size, void* d_ws, size_t ws_size,
                              hipStream_t stream) {
  const float* z0   = (const float*)d_in[0];
  const float* tdyn = (const float*)d_in[1];
  const float* Y    = (const float*)d_in[2];
  const float* M    = (const float*)d_in[3];
  const int*   lens = (const int*)d_in[4];
  const float* H    = (const float*)d_in[5];
  const float* Wih  = (const float*)d_in[6];
  const float* bih  = (const float*)d_in[7];
  const float* Whh  = (const float*)d_in[8];
  const float* bhh  = (const float*)d_in[9];
  const float* lgam = (const float*)d_in[10];
  float* out = (float*)d_out;  // f32: [B*DZ] z_final, then [B*T*DZ] Z_traj

  const size_t needF32 = (size_t)NB * NT * NG * sizeof(float);  // 201.3 MB
  dim3 ggrid((NB * NT) / GM, NG / GN);
  if (ws_size >= needF32) {
    float* gi = (float*)d_ws;
    gemm_gi<float><<<ggrid, 256, 0, stream>>>(Y, M, H, Wih, bih, gi);
    scan_m<float><<<dim3(NB / BPB), 512, 0, stream>>>(z0, tdyn, lens, Whh, bhh, lgam, gi, out);
  } else {
    u16* gi = (u16*)d_ws;  // bf16 gi (validated: absmax 3.9e-3)
    gemm_gi<u16><<<ggrid, 256, 0, stream>>>(Y, M, H, Wih, bih, gi);
    scan_m<u16><<<dim3(NB / BPB), 512, 0, stream>>>(z0, tdyn, lens, Whh, bhh, lgam, gi, out);
  }
}

// Round 7
// 2941.321 us; speedup vs baseline: 3.4871x; 3.4871x over previous
//
#include <hip/hip_runtime.h>
#include <hip/hip_bf16.h>
#include <stdint.h>

typedef unsigned short u16;
typedef __fp16 h2 __attribute__((ext_vector_type(2)));  // matches cvt_pkrtz/fdot2 builtin types

#define NB  32
#define NT  4096
#define NDZ 128
#define NG  384   // 3*DZ
#define NIN 192   // IN_DIM

#if defined(__has_builtin)
#if __has_builtin(__builtin_amdgcn_fdot2)
#define HAS_FDOT2 1
#endif
#endif

// ---------- helpers ----------
__device__ __forceinline__ float fast_rcp(float x) { return __builtin_amdgcn_rcpf(x); }
__device__ __forceinline__ float sigmoid_f(float x) { return fast_rcp(1.f + __expf(-x)); }
__device__ __forceinline__ float tanh_f(float x) {
  return 1.f - 2.f * fast_rcp(1.f + __expf(2.f * x));
}
__device__ __forceinline__ u16 f2bf(float f) {
  unsigned u = __float_as_uint(f);
  return (u16)((u + 0x7fffu + ((u >> 16) & 1u)) >> 16);
}
__device__ __forceinline__ float bf2f(u16 u) { return __uint_as_float((unsigned)u << 16); }

// LDS-only barrier (ds ops drained via lgkmcnt; vmcnt stays in flight so the
// t+2 gi prefetch and traj stores cross barriers without draining).
__device__ __forceinline__ void bar_lds() {
  asm volatile("s_waitcnt lgkmcnt(0)\n\ts_barrier" ::: "memory");
}

// gi workspace: bf16 validated (absmax 3.9e-3 << 5.9e-2); f32 if ws allows
__device__ __forceinline__ float giload(const float* p) { return *p; }
__device__ __forceinline__ float giload(const u16* p)   { return bf2f(*p); }
__device__ __forceinline__ void store8(float* p, const float* v) {
  float4 a = {v[0], v[1], v[2], v[3]}, b = {v[4], v[5], v[6], v[7]};
  *(float4*)p = a; *(float4*)(p + 4) = b;
}
__device__ __forceinline__ void store8(u16* p, const float* v) {
  uint4 o;
  o.x = (unsigned)f2bf(v[0]) | ((unsigned)f2bf(v[1]) << 16);
  o.y = (unsigned)f2bf(v[2]) | ((unsigned)f2bf(v[3]) << 16);
  o.z = (unsigned)f2bf(v[4]) | ((unsigned)f2bf(v[5]) << 16);
  o.w = (unsigned)f2bf(v[6]) | ((unsigned)f2bf(v[7]) << 16);
  *(uint4*)p = o;
}

// ---------- Phase 1: gi = x @ W_ih^T + b_ih (unchanged) ----------
#define GM 128
#define GN 128
#define LDSS 132

template <typename GT>
__global__ __launch_bounds__(256) void gemm_gi(
    const float* __restrict__ Y, const float* __restrict__ M,
    const float* __restrict__ H, const float* __restrict__ Wih,
    const float* __restrict__ bih, GT* __restrict__ gi)
{
  __shared__ float As[32 * LDSS];
  __shared__ float Bs[32 * LDSS];
  const int tid = threadIdx.x;
  const size_t m0 = (size_t)blockIdx.x * GM;
  const int n0 = blockIdx.y * GN;
  const int tm = tid & 15;
  const int tn = tid >> 4;

  float acc[8][8];
#pragma unroll
  for (int i = 0; i < 8; ++i)
#pragma unroll
    for (int j = 0; j < 8; ++j) acc[i][j] = 0.f;

#pragma unroll
  for (int kc = 0; kc < 6; ++kc) {
    const float* src; int stride; int off;
    if (kc == 0)      { src = Y; stride = 32;  off = 0; }
    else if (kc == 1) { src = M; stride = 32;  off = 0; }
    else              { src = H; stride = 128; off = (kc - 2) * 32; }
#pragma unroll
    for (int it = 0; it < 4; ++it) {
      int x = tid + it * 256;
      int row = x >> 3, q = x & 7;
      float4 v = *(const float4*)(src + (m0 + (size_t)row) * stride + off + q * 4);
      As[(q * 4 + 0) * LDSS + row] = v.x;
      As[(q * 4 + 1) * LDSS + row] = v.y;
      As[(q * 4 + 2) * LDSS + row] = v.z;
      As[(q * 4 + 3) * LDSS + row] = v.w;
    }
#pragma unroll
    for (int it = 0; it < 4; ++it) {
      int x = tid + it * 256;
      int g = x >> 3, q = x & 7;
      float4 v = *(const float4*)(Wih + (size_t)(n0 + g) * NIN + kc * 32 + q * 4);
      Bs[(q * 4 + 0) * LDSS + g] = v.x;
      Bs[(q * 4 + 1) * LDSS + g] = v.y;
      Bs[(q * 4 + 2) * LDSS + g] = v.z;
      Bs[(q * 4 + 3) * LDSS + g] = v.w;
    }
    __syncthreads();
#pragma unroll
    for (int kk = 0; kk < 32; ++kk) {
      float4 a0 = *(const float4*)&As[kk * LDSS + tm * 8];
      float4 a1 = *(const float4*)&As[kk * LDSS + tm * 8 + 4];
      float4 b0 = *(const float4*)&Bs[kk * LDSS + tn * 8];
      float4 b1 = *(const float4*)&Bs[kk * LDSS + tn * 8 + 4];
      float av[8] = {a0.x, a0.y, a0.z, a0.w, a1.x, a1.y, a1.z, a1.w};
      float bv[8] = {b0.x, b0.y, b0.z, b0.w, b1.x, b1.y, b1.z, b1.w};
#pragma unroll
      for (int i = 0; i < 8; ++i)
#pragma unroll
        for (int j = 0; j < 8; ++j)
          acc[i][j] = __builtin_fmaf(av[i], bv[j], acc[i][j]);
    }
    __syncthreads();
  }
  float bv[8];
#pragma unroll
  for (int j = 0; j < 8; ++j) bv[j] = bih[n0 + tn * 8 + j];
#pragma unroll
  for (int i = 0; i < 8; ++i) {
    size_t row = m0 + (size_t)(tm * 8 + i);
    GT* o = gi + row * NG + n0 + tn * 8;
    float v[8];
#pragma unroll
    for (int j = 0; j < 8; ++j) v[j] = acc[i][j] + bv[j];
    store8(o, v);
  }
}

// ---------- Phase 2: scan, 8 waves, fdot2 matvec, direct-read gates ----------
// R1-R3 invariant 1860 cyc/step decomposes as ~2x(matvec issue ~280) +
// ~2x(gates issue ~100) + ~400 fixed latency (LDS RT + barrier + shfl +
// trans chains). R4 proved per-CU work conservation kills MFMA (16-batch
// granularity -> 2 CUs). So: keep 32 blocks / R3 skeleton, halve matvec
// issue with v_dot2_f32_f16 (f16 weights: |w|<=0.088, 10-bit mantissa
// beats validated bf16-gi precision; f32 accumulate), and cut the gate
// chain by reading all 12 partials directly (lanes 32-63 are same-address
// broadcasts = free) instead of 8 reads + 2 dependent ds_bpermute shfls.
// z-pair packing for dot2: one shfl_xor(1) + cvt_pkrtz per step.
#define KS 32

template <typename GT>
__global__ __launch_bounds__(512, 2) void scan_k(
    const float* __restrict__ zinit, const float* __restrict__ tdyn,
    const int* __restrict__ lens, const float* __restrict__ Whh,
    const float* __restrict__ bhh, const float* __restrict__ lgam,
    const GT* __restrict__ gi, float* __restrict__ out)
{
  const int b = blockIdx.x;
  const int tid = threadIdx.x;   // 0..511
  const int lane = tid & 63;
  const int w = tid >> 6;        // wave 0..7
  const int s_idx = w & 3;       // K-slice
  const int h = w >> 2;          // row-half within slice pair
  const int k0 = s_idx * KS;
  const int e = lane & 31;
  const int j = k0 + e;          // owned elem (mirrored in lanes 32-63)

  __shared__ float P0[4][NG];    // 6 KB
  __shared__ float P1[4][NG];    // 6 KB

  // 3 weight rows per lane, K-slice [k0,k0+32)
  const int rowA = h * NDZ + lane;           // r (h=0) or u (h=1) rows
  const int rowB = rowA + 64;
  const int rowC = 2 * NDZ + h * 64 + lane;  // n rows, split by h
#ifdef HAS_FDOT2
  h2 wa[KS / 2], wb[KS / 2], wc[KS / 2];     // f16-packed pairs: 48 VGPRs
  {
    const float4* ra = (const float4*)(Whh + (size_t)rowA * NDZ + k0);
    const float4* rb = (const float4*)(Whh + (size_t)rowB * NDZ + k0);
    const float4* rc = (const float4*)(Whh + (size_t)rowC * NDZ + k0);
#pragma unroll
    for (int q = 0; q < 8; ++q) {
      float4 va = ra[q], vb = rb[q], vc = rc[q];
      wa[2 * q]     = __builtin_amdgcn_cvt_pkrtz(va.x, va.y);
      wa[2 * q + 1] = __builtin_amdgcn_cvt_pkrtz(va.z, va.w);
      wb[2 * q]     = __builtin_amdgcn_cvt_pkrtz(vb.x, vb.y);
      wb[2 * q + 1] = __builtin_amdgcn_cvt_pkrtz(vb.z, vb.w);
      wc[2 * q]     = __builtin_amdgcn_cvt_pkrtz(vc.x, vc.y);
      wc[2 * q + 1] = __builtin_amdgcn_cvt_pkrtz(vc.z, vc.w);
    }
  }
#else
  float wa[KS], wb[KS], wc[KS];
  {
    const float4* ra = (const float4*)(Whh + (size_t)rowA * NDZ + k0);
    const float4* rb = (const float4*)(Whh + (size_t)rowB * NDZ + k0);
    const float4* rc = (const float4*)(Whh + (size_t)rowC * NDZ + k0);
#pragma unroll
    for (int q = 0; q < 8; ++q) {
      float4 va = ra[q], vb = rb[q], vc = rc[q];
      wa[4 * q] = va.x; wa[4 * q + 1] = va.y; wa[4 * q + 2] = va.z; wa[4 * q + 3] = va.w;
      wb[4 * q] = vb.x; wb[4 * q + 1] = vb.y; wb[4 * q + 2] = vb.z; wb[4 * q + 3] = vb.w;
      wc[4 * q] = vc.x; wc[4 * q + 1] = vc.y; wc[4 * q + 2] = vc.z; wc[4 * q + 3] = vc.w;
    }
  }
#endif

  const int len = lens[b];
  const float* tp = tdyn + (size_t)b * NT;
  const GT* gb = gi + (size_t)b * NT * NG;
  float* traj = out + (size_t)NB * NDZ + (size_t)b * NT * NDZ;

  // per-elem state (mirrored across halves and h-waves; h=0/lane<32 stores)
  float zc = zinit[b * NDZ + j];
  const float lg = lgam[j];
  const float gam = (lg > 15.f) ? lg : __logf(1.f + __expf(lg));
  const float br = bhh[j], bu = bhh[NDZ + j], bn = bhh[2 * NDZ + j];
  float t_prev = tp[0];
  float zdr = zc;                // z_d(0) = z0 (dt0 = 0)

  // prefetch buffers (static names, no runtime index)
  float ptkA = tp[1];
  float ptkB = tp[2];
  float pgrA = giload(gb + j), pguA = giload(gb + NDZ + j), pgnA = giload(gb + 2 * NDZ + j);
  float pgrB = giload(gb + NG + j), pguB = giload(gb + NG + NDZ + j), pgnB = giload(gb + NG + 2 * NDZ + j);

  auto stepf = [&](float (*PB)[NG], float& ptkX, float& pgrX, float& pguX, float& pgnX, int t) {
    // ef for end-of-step zdr update: inputs prefetched -> off the serial chain
    const float tk = ptkX;
    const float ef = __expf(-gam * fmaxf(tk - t_prev, 0.f));
    t_prev = tk;

    const bool active = (t < len);  // block-uniform
    if (active) {
      float aa = 0.f, ab = 0.f, ac = 0.f;
#ifdef HAS_FDOT2
      // pack (z[k0+2m], z[k0+2m+1]) at even lanes: shfl_xor(1) + cvt_pkrtz
      const float zpartner = __shfl_xor(zdr, 1, 64);
      const h2 zpk = __builtin_amdgcn_cvt_pkrtz(zdr, zpartner);
      const int zpi = __builtin_bit_cast(int, zpk);
#pragma unroll
      for (int m = 0; m < KS / 2; ++m) {
        const int zi = __builtin_amdgcn_readlane(zpi, 2 * m);
        const h2 zk = __builtin_bit_cast(h2, zi);
        aa = __builtin_amdgcn_fdot2(wa[m], zk, aa, false);
        ab = __builtin_amdgcn_fdot2(wb[m], zk, ab, false);
        ac = __builtin_amdgcn_fdot2(wc[m], zk, ac, false);
      }
#else
#pragma unroll
      for (int k = 0; k < KS; ++k) {
        const float zk = __int_as_float(
            __builtin_amdgcn_readlane(__float_as_int(zdr), k));
        aa = __builtin_fmaf(wa[k], zk, aa);
        ab = __builtin_fmaf(wb[k], zk, ab);
        ac = __builtin_fmaf(wc[k], zk, ac);
      }
#endif
      PB[s_idx][rowA] = aa;
      PB[s_idx][rowB] = ab;
      PB[s_idx][rowC] = ac;
    }
    bar_lds();  // ONLY barrier of the step: partials published

    const float zd = zdr;
    if (active) {
      // direct 12-read gate sums (lanes 32-63: same-addr broadcast, free)
      const float* Pb = &PB[0][0];
      const float sr = (Pb[j] + Pb[NG + j]) + (Pb[2 * NG + j] + Pb[3 * NG + j]);
      const float su = (Pb[NDZ + j] + Pb[NG + NDZ + j]) +
                       (Pb[2 * NG + NDZ + j] + Pb[3 * NG + NDZ + j]);
      const float sn = (Pb[2 * NDZ + j] + Pb[NG + 2 * NDZ + j]) +
                       (Pb[2 * NG + 2 * NDZ + j] + Pb[3 * NG + 2 * NDZ + j]);
      const float r = sigmoid_f(sr + br + pgrX);
      const float u = sigmoid_f(su + bu + pguX);
      const float n = tanh_f(__builtin_fmaf(r, sn + bn, pgnX));
      zc = (1.f - u) * n + u * zd;
    } else {
      zc = zd;
    }
    if (h == 0 && lane < 32) traj[(size_t)t * NDZ + j] = zc;

    zdr = zc * ef;  // z_d(t+1): single mul on the chain

    // prefetch for step t+2 (clamped; values unused past the end)
    const int t2 = (t + 2 < NT) ? (t + 2) : (NT - 1);
    const int t3 = (t + 3 < NT) ? (t + 3) : (NT - 1);
    ptkX = tp[t3];
    const GT* g2 = gb + (size_t)t2 * NG;
    pgrX = giload(g2 + j);
    pguX = giload(g2 + NDZ + j);
    pgnX = giload(g2 + 2 * NDZ + j);
  };

  for (int t = 0; t < NT; t += 2) {
    stepf(P0, ptkA, pgrA, pguA, pgnA, t);
    stepf(P1, ptkB, pgrB, pguB, pgnB, t + 1);
  }
  if (h == 0 && lane < 32) out[b * NDZ + j] = zc;  // z_final
}

extern "C" void kernel_launch(void* const* d_in, const int* in_sizes, int n_in,
                              void* d_out, int out_size, void* d_ws, size_t ws_size,
                              hipStream_t stream) {
  const float* z0   = (const float*)d_in[0];
  const float* tdyn = (const float*)d_in[1];
  const float* Y    = (const float*)d_in[2];
  const float* M    = (const float*)d_in[3];
  const int*   lens = (const int*)d_in[4];
  const float* H    = (const float*)d_in[5];
  const float* Wih  = (const float*)d_in[6];
  const float* bih  = (const float*)d_in[7];
  const float* Whh  = (const float*)d_in[8];
  const float* bhh  = (const float*)d_in[9];
  const float* lgam = (const float*)d_in[10];
  float* out = (float*)d_out;  // f32: [B*DZ] z_final, then [B*T*DZ] Z_traj

  const size_t needF32 = (size_t)NB * NT * NG * sizeof(float);  // 201.3 MB
  dim3 ggrid((NB * NT) / GM, NG / GN);
  if (ws_size >= needF32) {
    float* gi = (float*)d_ws;
    gemm_gi<float><<<ggrid, 256, 0, stream>>>(Y, M, H, Wih, bih, gi);
    scan_k<float><<<dim3(NB), 512, 0, stream>>>(z0, tdyn, lens, Whh, bhh, lgam, gi, out);
  } else {
    u16* gi = (u16*)d_ws;  // bf16 gi (validated: absmax 3.9e-3)
    gemm_gi<u16><<<ggrid, 256, 0, stream>>>(Y, M, H, Wih, bih, gi);
    scan_k<u16><<<dim3(NB), 512, 0, stream>>>(z0, tdyn, lens, Whh, bhh, lgam, gi, out);
  }
}